// Round 1
// baseline (3077.434 us; speedup 1.0000x reference)
//
#include <hip/hip_runtime.h>
#include <math.h>

#define B_ 16
#define N_ 2048
#define KNN 20
#define BN_EPS 1e-5f
#define SLOPE 0.01f

// ============================================================ xx = sum_d x^2
__global__ __launch_bounds__(256) void xx_kernel(const float* __restrict__ xin, long bstr, int D,
                                                 float* __restrict__ xx) {
  int i = blockIdx.x * 256 + threadIdx.x;
  if (i >= B_ * N_) return;
  int b = i >> 11, n = i & (N_ - 1);
  const float* p = xin + (long)b * bstr + n;
  float s = 0.f;
#pragma unroll 1
  for (int d = 0; d < D; ++d) { float v = p[(long)d * N_]; s = fmaf(v, v, s); }
  xx[i] = s;
}

// ============================================================ (B,D,N) -> per-batch (N,D)
__global__ __launch_bounds__(256) void transpose_kernel(const float* __restrict__ xin, long bstr,
                                                        float* __restrict__ xT, long xTbstr, int D) {
  __shared__ float s[32][65];
  int b = blockIdx.y;
  int n0 = blockIdx.x * 64;
  int tid = threadIdx.x;
  const float* xb = xin + (long)b * bstr;
  float* tb = xT + (long)b * xTbstr;
  for (int dc = 0; dc < D; dc += 32) {
    for (int i = tid; i < 32 * 64; i += 256) {
      int d = i >> 6, n = i & 63;
      s[d][n] = (dc + d < D) ? xb[(long)(dc + d) * N_ + n0 + n] : 0.f;
    }
    __syncthreads();
    for (int i = tid; i < 64 * 32; i += 256) {
      int n = i >> 5, d = i & 31;
      if (dc + d < D) tb[(long)(n0 + n) * D + dc + d] = s[d][n];
    }
    __syncthreads();
  }
}

// ============================================================ gsa: dist row + top-20 + softmax + agg
template <int D>
__global__ __launch_bounds__(256) void gsa_kernel(const float* __restrict__ xin, long bstr,
                                                  const float* __restrict__ xT, long xTbstr,
                                                  const float* __restrict__ xx,
                                                  float* __restrict__ agg, long aggbstr) {
  __shared__ float xn_s[4][((D + 3) / 4) * 4];
  int tid = threadIdx.x, w = tid >> 6, lane = tid & 63;
  int r = blockIdx.x * 4 + w;
  int b = r >> 11, n = r & (N_ - 1);
  const float* tb = xT + (long)b * xTbstr;
  for (int d = lane; d < D; d += 64) xn_s[w][d] = tb[(long)n * D + d];
  __syncthreads();
  float xxn = xx[b * N_ + n];
  float acc[8][4];
#pragma unroll
  for (int c = 0; c < 8; ++c) { acc[c][0] = 0.f; acc[c][1] = 0.f; acc[c][2] = 0.f; acc[c][3] = 0.f; }
  const float* xb = xin + (long)b * bstr;
#pragma unroll 4
  for (int d = 0; d < D; ++d) {
    float xnd = xn_s[w][d];
    const float4* row = (const float4*)(xb + (long)d * N_);
#pragma unroll
    for (int c = 0; c < 8; ++c) {
      float4 v = row[c * 64 + lane];
      acc[c][0] = fmaf(xnd, v.x, acc[c][0]);
      acc[c][1] = fmaf(xnd, v.y, acc[c][1]);
      acc[c][2] = fmaf(xnd, v.z, acc[c][2]);
      acc[c][3] = fmaf(xnd, v.w, acc[c][3]);
    }
  }
  float dv[8][4];
  const float4* xx4 = (const float4*)(xx + b * N_);
#pragma unroll
  for (int c = 0; c < 8; ++c) {
    float4 xm = xx4[c * 64 + lane];
    dv[c][0] = 2.f * acc[c][0] - xxn - xm.x;
    dv[c][1] = 2.f * acc[c][1] - xxn - xm.y;
    dv[c][2] = 2.f * acc[c][2] - xxn - xm.z;
    dv[c][3] = 2.f * acc[c][3] - xxn - xm.w;
  }
  // ---- top-20 by iterative wave argmax (value desc, index asc on ties) ----
  float sval[KNN];
  int sidx[KNN];
  int mbase = lane << 2;
#pragma unroll
  for (int it = 0; it < KNN; ++it) {
    float best = dv[0][0];
    int bidx = mbase;
#pragma unroll
    for (int c = 0; c < 8; ++c)
#pragma unroll
      for (int j = 0; j < 4; ++j) {
        if (c == 0 && j == 0) continue;
        if (dv[c][j] > best) { best = dv[c][j]; bidx = c * 256 + mbase + j; }
      }
#pragma unroll
    for (int off = 1; off < 64; off <<= 1) {
      float ov = __shfl_xor(best, off);
      int oi = __shfl_xor(bidx, off);
      if (ov > best || (ov == best && oi < bidx)) { best = ov; bidx = oi; }
    }
    sval[it] = best;
    sidx[it] = bidx;
#pragma unroll
    for (int c = 0; c < 8; ++c)
#pragma unroll
      for (int j = 0; j < 4; ++j)
        if (bidx == c * 256 + mbase + j) dv[c][j] = -3.4e38f;
  }
  // ---- softmax over the 20 (sval[0] is the max) ----
  float wgt[KNN], Z = 0.f;
#pragma unroll
  for (int k = 0; k < KNN; ++k) { wgt[k] = __expf(sval[k] - sval[0]); Z += wgt[k]; }
  float rZ = 1.f / Z;
#pragma unroll
  for (int k = 0; k < KNN; ++k) wgt[k] *= rZ;
  // ---- agg[d] = sum_k w_k * (x[d, idx_k] - x[d, n]) ----
  for (int dd = lane; dd < D; dd += 64) {
    float xnd = xn_s[w][dd];
    float a = 0.f;
#pragma unroll
    for (int k = 0; k < KNN; ++k) a = fmaf(wgt[k], tb[(long)sidx[k] * D + dd] - xnd, a);
    agg[(long)b * aggbstr + (long)dd * N_ + n] = a;
  }
}

// ============================================================ GEMM (O,K)x(K, B*N) + BN stats
__global__ __launch_bounds__(256) void gemm_bn_kernel(const float* __restrict__ Wm, int O, int K,
                                                      const float* __restrict__ xin, long bstr, int Dx,
                                                      const float* __restrict__ agg, long aggbstr,
                                                      float* __restrict__ y, float* __restrict__ stats) {
  __shared__ __align__(16) float As[16][68];
  __shared__ __align__(16) float Bs[16][68];
  int tid = threadIdx.x;
  int o0 = blockIdx.x * 64;
  int j0 = blockIdx.y * 64;
  int b = j0 >> 11, n0 = j0 & (N_ - 1);
  int ty = tid >> 4, tx = tid & 15;
  float accr[4][4] = {};
  int aK = tid & 15, aO = tid >> 4;
  int bK = tid >> 4, bn4 = (tid & 15) << 2;
  for (int k0 = 0; k0 < K; k0 += 16) {
#pragma unroll
    for (int q = 0; q < 4; ++q) {
      int o = aO + (q << 4);
      As[aK][o] = (k0 + aK < K) ? Wm[(long)(o0 + o) * K + k0 + aK] : 0.f;
    }
    {
      int c = k0 + bK;
      float4 v = {0.f, 0.f, 0.f, 0.f};
      if (c < K) {
        const float* src = (c < Dx) ? xin + (long)b * bstr + (long)c * N_
                                    : agg + (long)b * aggbstr + (long)(c - Dx) * N_;
        v = *(const float4*)(src + n0 + bn4);
      }
      *(float4*)&Bs[bK][bn4] = v;
    }
    __syncthreads();
#pragma unroll
    for (int kk = 0; kk < 16; ++kk) {
      float4 a4 = *(const float4*)&As[kk][ty << 2];
      float4 b4 = *(const float4*)&Bs[kk][tx << 2];
      accr[0][0] = fmaf(a4.x, b4.x, accr[0][0]);
      accr[0][1] = fmaf(a4.x, b4.y, accr[0][1]);
      accr[0][2] = fmaf(a4.x, b4.z, accr[0][2]);
      accr[0][3] = fmaf(a4.x, b4.w, accr[0][3]);
      accr[1][0] = fmaf(a4.y, b4.x, accr[1][0]);
      accr[1][1] = fmaf(a4.y, b4.y, accr[1][1]);
      accr[1][2] = fmaf(a4.y, b4.z, accr[1][2]);
      accr[1][3] = fmaf(a4.y, b4.w, accr[1][3]);
      accr[2][0] = fmaf(a4.z, b4.x, accr[2][0]);
      accr[2][1] = fmaf(a4.z, b4.y, accr[2][1]);
      accr[2][2] = fmaf(a4.z, b4.z, accr[2][2]);
      accr[2][3] = fmaf(a4.z, b4.w, accr[2][3]);
      accr[3][0] = fmaf(a4.w, b4.x, accr[3][0]);
      accr[3][1] = fmaf(a4.w, b4.y, accr[3][1]);
      accr[3][2] = fmaf(a4.w, b4.z, accr[3][2]);
      accr[3][3] = fmaf(a4.w, b4.w, accr[3][3]);
    }
    __syncthreads();
  }
#pragma unroll
  for (int r = 0; r < 4; ++r) {
    int o = o0 + (ty << 2) + r;
    float4 v;
    v.x = accr[r][0]; v.y = accr[r][1]; v.z = accr[r][2]; v.w = accr[r][3];
    *(float4*)(y + ((long)b * O + o) * N_ + n0 + bn4) = v;
    float s1 = v.x + v.y + v.z + v.w;
    float s2 = v.x * v.x + v.y * v.y + v.z * v.z + v.w * v.w;
#pragma unroll
    for (int off = 1; off < 16; off <<= 1) { s1 += __shfl_xor(s1, off); s2 += __shfl_xor(s2, off); }
    if (tx == 0) { atomicAdd(&stats[o], s1); atomicAdd(&stats[O + o], s2); }
  }
}

// ============================================================ fold BN stats into scale/shift
__global__ __launch_bounds__(256) void bn_finalize_kernel(float* __restrict__ stats,
                                                          const float* __restrict__ g,
                                                          const float* __restrict__ be, int O) {
  int o = blockIdx.x * 256 + threadIdx.x;
  if (o >= O) return;
  const float inv_cnt = 1.f / (B_ * (float)N_);
  float mean = stats[o] * inv_cnt;
  float var = stats[O + o] * inv_cnt - mean * mean;
  float a = g[o] * rsqrtf(var + BN_EPS);
  float bb = be[o] - mean * a;
  stats[o] = a;
  stats[O + o] = bb;
}

// ============================================================ y -> lrelu(a*y+b) -> dst (+dst2)
__global__ __launch_bounds__(256) void bn_apply_kernel(const float* __restrict__ y,
                                                       const float* __restrict__ stats, int O,
                                                       float* __restrict__ dst, int c0, int dstStride,
                                                       float* __restrict__ dst2) {
  long i4 = (long)blockIdx.x * 256 + threadIdx.x;
  long total4 = (long)B_ * O * N_ / 4;
  if (i4 >= total4) return;
  long i = i4 << 2;
  int ob = __ffs(O) - 1;
  int o = (int)((i >> 11) & (O - 1));
  int b = (int)(i >> (11 + ob));
  int n = (int)(i & (N_ - 1));
  float a = stats[o], bb = stats[O + o];
  float4 v = *(const float4*)(y + i);
  v.x = fmaf(a, v.x, bb); v.x = v.x >= 0.f ? v.x : SLOPE * v.x;
  v.y = fmaf(a, v.y, bb); v.y = v.y >= 0.f ? v.y : SLOPE * v.y;
  v.z = fmaf(a, v.z, bb); v.z = v.z >= 0.f ? v.z : SLOPE * v.z;
  v.w = fmaf(a, v.w, bb); v.w = v.w >= 0.f ? v.w : SLOPE * v.w;
  *(float4*)(dst + ((long)b * dstStride + c0 + o) * N_ + n) = v;
  if (dst2) *(float4*)(dst2 + i) = v;
}

// ============================================================ launcher
extern "C" void kernel_launch(void* const* d_in, const int* in_sizes, int n_in,
                              void* d_out, int out_size, void* d_ws, size_t ws_size,
                              hipStream_t stream) {
  const float* x = (const float*)d_in[0];
  const float* W[5];
  const float* gm[5];
  const float* bt[5];
  for (int i = 0; i < 5; ++i) W[i] = (const float*)d_in[1 + i];
  for (int i = 0; i < 5; ++i) { gm[i] = (const float*)d_in[6 + 2 * i]; bt[i] = (const float*)d_in[7 + 2 * i]; }

  const long XBS = 512L * N_;                     // xall per-batch stride (floats)
  float* xall = (float*)d_ws;                     // (B, 512, N): x1@ch0, x2@ch64, x3@ch128, x4@ch256
  float* xxb = xall + (long)B_ * XBS;             // (B, N)
  float* stats = xxb + (long)B_ * N_;             // 5 * 1024
  float* xTb = xall + 256L * N_;                  // per-batch (N, D) in xall ch256..383 (spare until L4 apply)
  float* aggb = xall + 384L * N_;                 // per-batch (D, N) in xall ch384..511
  float* yb = (float*)d_out;                      // (B, O, N), max = x5 slot exactly
  float* outB = (float*)d_out + (long)B_ * XBS;   // x3 output slot

  hipMemsetAsync(stats, 0, 5 * 1024 * sizeof(float), stream);

  struct LayerCfg { const float* xin; long bstr; int D; int O; int c0; };
  LayerCfg L[4] = {
      {x, 3L * N_, 3, 64, 0},
      {xall, XBS, 64, 64, 64},
      {xall + 64L * N_, XBS, 64, 128, 128},
      {xall + 128L * N_, XBS, 128, 256, 256},
  };

  for (int li = 0; li < 4; ++li) {
    const LayerCfg c = L[li];
    float* st = stats + li * 1024;
    xx_kernel<<<B_ * N_ / 256, 256, 0, stream>>>(c.xin, c.bstr, c.D, xxb);
    transpose_kernel<<<dim3(N_ / 64, B_), 256, 0, stream>>>(c.xin, c.bstr, xTb, XBS, c.D);
    if (c.D == 3)
      gsa_kernel<3><<<B_ * N_ / 4, 256, 0, stream>>>(c.xin, c.bstr, xTb, XBS, xxb, aggb, XBS);
    else if (c.D == 64)
      gsa_kernel<64><<<B_ * N_ / 4, 256, 0, stream>>>(c.xin, c.bstr, xTb, XBS, xxb, aggb, XBS);
    else
      gsa_kernel<128><<<B_ * N_ / 4, 256, 0, stream>>>(c.xin, c.bstr, xTb, XBS, xxb, aggb, XBS);
    gemm_bn_kernel<<<dim3(c.O / 64, B_ * N_ / 64), 256, 0, stream>>>(
        W[li], c.O, 2 * c.D, c.xin, c.bstr, c.D, aggb, XBS, yb, st);
    bn_finalize_kernel<<<(c.O + 255) / 256, 256, 0, stream>>>(st, gm[li], bt[li], c.O);
    long t4 = (long)B_ * c.O * N_ / 4;
    bn_apply_kernel<<<(int)((t4 + 255) / 256), 256, 0, stream>>>(
        yb, st, c.O, xall, c.c0, 512, (li == 2) ? outB : nullptr);
  }
  // layer 5: plain conv on the concat (xall ch0..511), no gsa
  {
    float* st = stats + 4 * 1024;
    gemm_bn_kernel<<<dim3(512 / 64, B_ * N_ / 64), 256, 0, stream>>>(
        W[4], 512, 512, xall, XBS, 512, nullptr, XBS, yb, st);
    bn_finalize_kernel<<<2, 256, 0, stream>>>(st, gm[4], bt[4], 512);
    long t4 = (long)B_ * 512 * N_ / 4;
    bn_apply_kernel<<<(int)((t4 + 255) / 256), 256, 0, stream>>>(yb, st, 512, yb, 0, 512, nullptr);
  }
}